// Round 12
// baseline (244.239 us; speedup 1.0000x reference)
//
#include <hip/hip_runtime.h>
#include <cstdint>
#include <cstddef>

// ---------------------------------------------------------------------------
// 3-layer GCN, fp16 message pipeline, 9 dispatches:
//   k_prep | k_bucket | k_build | {gemm, agg} x3  (agg64 fuses log_softmax)
// agg128 is FEATURE-CHUNKED (4 chunks x 32 feats = 64B line): per-chunk
// gather footprint 3.2MB fits in one XCD's 4MB L2; chunk-major blockIdx
// ordering keeps one chunk live at a time -> gathers served from L2.
// Lessons: R8 coop mega-kernel 3.7x slower; R10 atomic padding null;
// R11 two-phase ELL build == single-phase (rocprof per-kernel durs are
// cold-cache inflated by 256MiB flush fills — trust end-to-end dur only).
// ---------------------------------------------------------------------------

#define WAVE 64
#define ELLW 64
#define NSH  8     // shards per bucket (~XCD-private append tails)
#define BCAP 96    // per (bucket,shard) capacity; mean ~25
typedef _Float16 f16;
typedef f16  f16x2 __attribute__((ext_vector_type(2)));
typedef f16  f16x4 __attribute__((ext_vector_type(4)));
typedef f16  f16x8 __attribute__((ext_vector_type(8)));
typedef float f32x4 __attribute__((ext_vector_type(4)));

// ------------------------------ setup --------------------------------------

__global__ __launch_bounds__(256) void k_prep(int4* __restrict__ cur4, int n4,
                                              const float* __restrict__ W1,
                                              const float* __restrict__ W2,
                                              const float* __restrict__ Wf,
                                              f16* __restrict__ Wt1,
                                              f16* __restrict__ Wt2,
                                              f16* __restrict__ Wtf) {
    const int gtid = blockIdx.x * 256 + threadIdx.x;
    const int gsz  = gridDim.x * 256;
    const int4 z = make_int4(0, 0, 0, 0);
    for (int i = gtid; i < n4; i += gsz) cur4[i] = z;
    for (int i = gtid; i < 40960; i += gsz) {
        if (i < 16384) {
            int n = i >> 7, k = i & 127;
            Wt1[i] = (f16)W1[k * 128 + n];
        } else if (i < 32768) {
            int j = i - 16384;
            int n = j >> 7, k = j & 127;
            Wt2[j] = (f16)W2[k * 128 + n];
        } else {
            int j = i - 32768;
            int n = j >> 7, k = j & 127;
            Wtf[j] = (f16)Wf[k * 64 + n];
        }
    }
}

// pass 1: scatter edges into sharded dst-range buckets.
__global__ void k_bucket(const int* __restrict__ src, const int* __restrict__ dst, int E,
                         int* __restrict__ cur, int* __restrict__ bsh, int N) {
    int e = blockIdx.x * blockDim.x + threadIdx.x;
    if (e >= E) return;
    int d = dst[e], s = src[e];
    if ((unsigned)d >= (unsigned)N || (unsigned)s >= (unsigned)N) return;
    int b  = d >> 4;
    int sh = blockIdx.x & (NSH - 1);
    int p  = atomicAdd(&cur[b * NSH + sh], 1);
    if (p < BCAP)
        bsh[(size_t)(b * NSH + sh) * BCAP + p] = ((d & 15) << 16) | s;
}

// pass 2: block per bucket -> ELL rows + cnt.
__global__ __launch_bounds__(256) void k_build(const int* __restrict__ cur,
                                               const int* __restrict__ bsh,
                                               int* __restrict__ ell,
                                               int* __restrict__ cnt, int N) {
    __shared__ int lcnt[16];
    __shared__ int pre[NSH + 1];
    const int b = blockIdx.x;
    const int t = threadIdx.x;
    if (t < 16) lcnt[t] = 0;
    if (t == 0) {
        int acc = 0;
#pragma unroll
        for (int s2 = 0; s2 < NSH; ++s2) {
            pre[s2] = acc;
            int c = cur[b * NSH + s2];
            acc += (c < BCAP ? c : BCAP);
        }
        pre[NSH] = acc;
    }
    __syncthreads();
    const int total = pre[NSH];
    for (int i = t; i < total; i += 256) {
        int s2 = 0;
        while (pre[s2 + 1] <= i) ++s2;           // <=7 iters
        int v   = bsh[(size_t)(b * NSH + s2) * BCAP + (i - pre[s2])];
        int ld  = v >> 16;
        int sa  = v & 0xFFFF;
        int slot = atomicAdd(&lcnt[ld], 1);      // LDS atomic
        if (slot < ELLW)
            ell[(size_t)(b * 16 + ld) * ELLW + slot] = sa;
    }
    __syncthreads();
    if (t < 16) {
        int node = b * 16 + t;
        if (node < N) cnt[node] = lcnt[t];       // counts ALL edges (exact dinv)
    }
}

// ------------------------------ MFMA GEMM ----------------------------------
// M16[m][n] = ( A[m][:] @ W[:][n] ) * rsqrt(cnt[m]+1),  K=128 fixed.
template <int OUT, bool AF32>
__global__ __launch_bounds__(256) void k_gemm_mfma(const void* __restrict__ Av,
                                                   const f16* __restrict__ Wt,
                                                   const int* __restrict__ cnt,
                                                   f16* __restrict__ M,
                                                   int N) {
    constexpr int K  = 128;
    constexpr int CW = OUT / 64;          // col-tiles per wave (2 or 1)
    __shared__ char smem[OUT * K * 2];    // W (swizzled), then reused as out-tile
    __shared__ float dl[64];

    const int t    = threadIdx.x;
    const int w    = t >> 6;
    const int lane = t & 63;
    const int ln   = lane & 15;
    const int lh   = lane >> 4;
    const int row0 = blockIdx.x * 64;

    {
        constexpr int NCH = OUT * 16;     // 16 x 16B chunks per 256B row
        for (int j = t; j < NCH; j += 256) {
            int n = j >> 4;
            uint32_t byte = (uint32_t)j * 16;
            uint32_t swz  = byte ^ (uint32_t)((n & 7) << 4);
            *(f16x8*)(smem + swz) = *(const f16x8*)&Wt[(size_t)j * 8];
        }
        if (t < 64) {
            int r = row0 + t;
            dl[t] = rsqrtf((float)(cnt[r < N ? r : (N - 1)] + 1));
        }
    }
    __syncthreads();

    f16x8 bfr[CW][4];
    const int c0 = w * CW;
#pragma unroll
    for (int c = 0; c < CW; ++c) {
        int n = (c0 + c) * 16 + ln;
#pragma unroll
        for (int q = 0; q < 4; ++q) {
            uint32_t byte = (uint32_t)(n * 256 + q * 64 + lh * 16);
            uint32_t swz  = byte ^ (uint32_t)((n & 7) << 4);
            bfr[c][q] = *(const f16x8*)(smem + swz);
        }
    }
    __syncthreads();

    f32x4 acc[4][CW];
#pragma unroll
    for (int s = 0; s < 4; ++s)
#pragma unroll
        for (int c = 0; c < CW; ++c)
            acc[s][c] = f32x4{0.f, 0.f, 0.f, 0.f};

#pragma unroll
    for (int s = 0; s < 4; ++s) {
        int m = row0 + s * 16 + ln;
        const size_t mrow = (size_t)(m < N ? m : (N - 1)) * K;
#pragma unroll
        for (int q = 0; q < 4; ++q) {
            f16x8 a;
            if constexpr (AF32) {
                const float* ap = (const float*)Av + mrow + q * 32 + lh * 8;
                float4 x0 = *(const float4*)ap;
                float4 x1 = *(const float4*)(ap + 4);
                a = f16x8{ (f16)x0.x, (f16)x0.y, (f16)x0.z, (f16)x0.w,
                           (f16)x1.x, (f16)x1.y, (f16)x1.z, (f16)x1.w };
            } else {
                a = *(const f16x8*)((const f16*)Av + mrow + q * 32 + lh * 8);
            }
#pragma unroll
            for (int c = 0; c < CW; ++c)
                acc[s][c] = __builtin_amdgcn_mfma_f32_16x16x32_f16(a, bfr[c][q], acc[s][c], 0, 0, 0);
        }
    }

    f16* ot = (f16*)smem;
#pragma unroll
    for (int s = 0; s < 4; ++s) {
#pragma unroll
        for (int c = 0; c < CW; ++c) {
            int col = (c0 + c) * 16 + ln;
#pragma unroll
            for (int r = 0; r < 4; ++r) {
                int rl = s * 16 + lh * 4 + r;
                ot[rl * OUT + col] = (f16)(acc[s][c][r] * dl[rl]);
            }
        }
    }
    __syncthreads();

    constexpr int CPR = OUT / 8;          // 16B chunks per row
    for (int j = t; j < 64 * CPR; j += 256) {
        int rl = j / CPR;
        if (row0 + rl < N)
            *(f16x8*)&M[(size_t)(row0 + rl) * OUT + (j % CPR) * 8] =
                *(const f16x8*)&ot[(size_t)j * 8];
    }
}

// ------------------------------ aggregation --------------------------------
// FEATURE-CHUNKED agg128: grid = 4 chunks x (N/4 blocks), chunk-major so one
// 3.2MB chunk table is L2-live at a time. Wave = 1 node; 4 quarter-waves
// (16 lanes x f16x2 = 64B = one line) x unroll 4 = 16 edges per masked round.
__global__ __launch_bounds__(256) void k_agg128_c(const f16* __restrict__ M16,
                                                  const int* __restrict__ ell,
                                                  const int* __restrict__ cnt,
                                                  const float* __restrict__ bias,
                                                  f16* __restrict__ H16, int N,
                                                  int nbPer) {
    const int chunk = blockIdx.x / nbPer;       // 0..3 (chunk-major order)
    const int nb    = blockIdx.x - chunk * nbPer;
    const int wid   = threadIdx.x >> 6;
    const int lane  = threadIdx.x & (WAVE - 1);
    const int q     = lane >> 4;                // quarter 0..3
    const int fl    = lane & 15;
    const int node  = nb * 4 + wid;
    if (node >= N) return;
    const int fo = chunk * 32 + fl * 2;         // this wave's 2 feats

    float a0 = 0.f, a1 = 0.f;
    if (q == 0) {   // self-loop term
        f16x2 v = *(const f16x2*)&M16[(size_t)node * 128 + fo];
        a0 = (float)v.x; a1 = (float)v.y;
    }

    const int deg = cnt[node];
    const int e1  = deg < ELLW ? deg : ELLW;
    const int* erow = ell + (size_t)node * ELLW;
    for (int base = 0; base < e1; base += 16) {
        int   s[4];
        float w[4];
#pragma unroll
        for (int j = 0; j < 4; ++j) {
            int i = base + 4 * j + q;
            bool ok = i < e1;
            s[j] = erow[ok ? i : 0];
            w[j] = ok ? 1.f : 0.f;
        }
        f16x2 v[4];
#pragma unroll
        for (int j = 0; j < 4; ++j)
            v[j] = *(const f16x2*)&M16[(size_t)s[j] * 128 + fo];
#pragma unroll
        for (int j = 0; j < 4; ++j) {
            a0 += w[j] * (float)v[j].x;
            a1 += w[j] * (float)v[j].y;
        }
    }

    a0 += __shfl_xor(a0, 16);
    a0 += __shfl_xor(a0, 32);
    a1 += __shfl_xor(a1, 16);
    a1 += __shfl_xor(a1, 32);

    if (q == 0) {
        const float dn = rsqrtf((float)(deg + 1));
        float2 b = *(const float2*)&bias[fo];
        f16x2 o = { (f16)fmaxf(a0 * dn + b.x, 0.f),
                    (f16)fmaxf(a1 * dn + b.y, 0.f) };
        *(f16x2*)&H16[(size_t)node * 128 + fo] = o;
    }
}

// Final layer: 64 feats (128B row = 16 lanes x f16x4); half-wave per node,
// 16 edges per masked round; fused bias + log_softmax. (Not chunked: softmax
// needs all 64 classes; single pass, 6.4MB table.)
__global__ __launch_bounds__(256) void k_agg64_lsm(const f16* __restrict__ M16,
                                                   const int* __restrict__ ell,
                                                   const int* __restrict__ cnt,
                                                   const float* __restrict__ bias,
                                                   float* __restrict__ Y, int N) {
    const int lane = threadIdx.x & (WAVE - 1);
    const int sub  = lane >> 5;
    const int q    = (lane & 31) >> 4;
    const int fl   = lane & 15;            // classes 4*fl .. 4*fl+3
    const int fo   = fl * 4;
    const int node = blockIdx.x * 8 + ((threadIdx.x >> 6) << 1) + sub;
    if (node >= N) return;

    float a[4] = {0.f, 0.f, 0.f, 0.f};
    if (q == 0) {
        f16x4 v = *(const f16x4*)&M16[(size_t)node * 64 + fo];
#pragma unroll
        for (int i = 0; i < 4; ++i) a[i] = (float)v[i];
    }

    const int deg = cnt[node];
    const int e1  = deg < ELLW ? deg : ELLW;
    const int* erow = ell + (size_t)node * ELLW;
    for (int base = 0; base < e1; base += 16) {
        int   s[8];
        float w[8];
#pragma unroll
        for (int j = 0; j < 8; ++j) {
            int i = base + 2 * j + q;
            bool ok = i < e1;
            s[j] = erow[ok ? i : 0];
            w[j] = ok ? 1.f : 0.f;
        }
        f16x4 v[8];
#pragma unroll
        for (int j = 0; j < 8; ++j)
            v[j] = *(const f16x4*)&M16[(size_t)s[j] * 64 + fo];
#pragma unroll
        for (int j = 0; j < 8; ++j)
#pragma unroll
            for (int i = 0; i < 4; ++i)
                a[i] += w[j] * (float)v[j][i];
    }

#pragma unroll
    for (int i = 0; i < 4; ++i) a[i] += __shfl_xor(a[i], 16);

    const float dn = rsqrtf((float)(deg + 1));
    float4 b = *(const float4*)&bias[fo];
    float v0 = a[0] * dn + b.x;
    float v1 = a[1] * dn + b.y;
    float v2 = a[2] * dn + b.z;
    float v3 = a[3] * dn + b.w;
    float m = fmaxf(fmaxf(v0, v1), fmaxf(v2, v3));
#pragma unroll
    for (int o = 8; o > 0; o >>= 1) m = fmaxf(m, __shfl_xor(m, o));   // width-16
    float s = expf(v0 - m) + expf(v1 - m) + expf(v2 - m) + expf(v3 - m);
#pragma unroll
    for (int o = 8; o > 0; o >>= 1) s += __shfl_xor(s, o);
    if (q == 0) {
        float ls = logf(s);
        float4 o4 = make_float4(v0 - m - ls, v1 - m - ls, v2 - m - ls, v3 - m - ls);
        *(float4*)&Y[(size_t)node * 64 + fo] = o4;
    }
}

// ---------------------------------------------------------------------------

extern "C" void kernel_launch(void* const* d_in, const int* in_sizes, int n_in,
                              void* d_out, int out_size, void* d_ws, size_t ws_size,
                              hipStream_t stream) {
    const float* x  = (const float*)d_in[0];
    const int*   ei = (const int*)d_in[1];
    const float* W1 = (const float*)d_in[2];
    const float* b1 = (const float*)d_in[3];
    const float* W2 = (const float*)d_in[4];
    const float* b2 = (const float*)d_in[5];
    const float* Wf = (const float*)d_in[6];
    const float* bf = (const float*)d_in[7];
    float* out = (float*)d_out;

    const int N = in_sizes[0] / 128;
    const int E = in_sizes[1] / 2;
    const int* srcv = ei;
    const int* dstv = ei + E;

    char* ws = (char*)d_ws;
    auto alloc = [&](size_t bytes) -> void* {
        void* p = ws;
        ws += (bytes + 255) & ~(size_t)255;
        return p;
    };
    const int nbuck = (N + 15) / 16;
    int*   cur    = (int*)alloc((size_t)nbuck * NSH * 4 + 16);
    int*   bsh    = (int*)alloc((size_t)nbuck * NSH * BCAP * 4);
    int*   cnt    = (int*)alloc((size_t)N * 4);
    int*   ell    = (int*)alloc((size_t)N * ELLW * 4);
    f16*   m16    = (f16*)alloc((size_t)N * 128 * 2);
    f16*   h16    = (f16*)alloc((size_t)N * 128 * 2);
    f16*   Wt1    = (f16*)alloc(128 * 128 * 2);
    f16*   Wt2    = (f16*)alloc(128 * 128 * 2);
    f16*   Wtf    = (f16*)alloc(128 * 64 * 2);

    const int TB = 256;
    const int n4 = (nbuck * NSH + 3) / 4;

    k_prep<<<224, TB, 0, stream>>>((int4*)cur, n4, W1, W2, Wf, Wt1, Wt2, Wtf);
    k_bucket<<<(E + TB - 1) / TB, TB, 0, stream>>>(srcv, dstv, E, cur, bsh, N);
    k_build<<<nbuck, TB, 0, stream>>>(cur, bsh, ell, cnt, N);

    const int gemm_grid = (N + 63) / 64;
    const int nbPer     = (N + 3) / 4;        // agg128 blocks per chunk
    const int agg_grid  = 4 * nbPer;          // chunk-major
    const int agg64_grid = (N + 7) / 8;

    k_gemm_mfma<128, true><<<gemm_grid, 256, 0, stream>>>(x, Wt1, cnt, m16, N);
    k_agg128_c<<<agg_grid, 256, 0, stream>>>(m16, ell, cnt, b1, h16, N, nbPer);

    k_gemm_mfma<128, false><<<gemm_grid, 256, 0, stream>>>(h16, Wt2, cnt, m16, N);
    k_agg128_c<<<agg_grid, 256, 0, stream>>>(m16, ell, cnt, b2, h16, N, nbPer);

    k_gemm_mfma<64, false><<<gemm_grid, 256, 0, stream>>>(h16, Wtf, cnt, m16, N);
    k_agg64_lsm<<<agg64_grid, 256, 0, stream>>>(m16, ell, cnt, bf, out, N);
}

// Round 13
// 189.756 us; speedup vs baseline: 1.2871x; 1.2871x over previous
//
#include <hip/hip_runtime.h>
#include <cstdint>
#include <cstddef>

// ---------------------------------------------------------------------------
// 3-layer GCN, fp16 message pipeline, 8 dispatches:
//   k_prep (zero cnt + cvt weights) | k_fill (ELL build) |
//   {gemm, agg} x3  (agg64 fuses bias + log_softmax)
// ELL width 64 (deg ~ Poisson(12.5), P(deg>64)<1e-30; cnt counts ALL edges
// so dinv = rsqrt(deg+1) stays exact even if capped).
// Aggregation: half-wave per node; 32-edge masked round (16 row-loads in
// flight per half-wave) -> deg<=32 (97% of nodes) = ONE memory round.
// Lessons: R8 coop mega-kernel 3.7x slower; R10 atomic-line padding null;
// R11 two-phase ELL build null; R12 feature-chunking -80us (MLP halved,
// rounds x4 — in-flight loads dominate, L3 already absorbs the gather).
// rocprof per-kernel durs are cold-cache inflated by 256MiB flush fills —
// trust end-to-end dur only.
// ---------------------------------------------------------------------------

#define WAVE 64
#define ELLW 64
typedef _Float16 f16;
typedef f16  f16x4 __attribute__((ext_vector_type(4)));
typedef f16  f16x8 __attribute__((ext_vector_type(8)));
typedef float f32x4 __attribute__((ext_vector_type(4)));

// ------------------------------ setup --------------------------------------

// zero cnt (int4 stores) + all three weight transposes, one dispatch.
__global__ __launch_bounds__(256) void k_prep(int4* __restrict__ cnt4, int n4,
                                              const float* __restrict__ W1,
                                              const float* __restrict__ W2,
                                              const float* __restrict__ Wf,
                                              f16* __restrict__ Wt1,
                                              f16* __restrict__ Wt2,
                                              f16* __restrict__ Wtf) {
    const int gtid = blockIdx.x * 256 + threadIdx.x;
    const int gsz  = gridDim.x * 256;
    const int4 z = make_int4(0, 0, 0, 0);
    for (int i = gtid; i < n4; i += gsz) cnt4[i] = z;
    for (int i = gtid; i < 40960; i += gsz) {
        if (i < 16384) {
            int n = i >> 7, k = i & 127;
            Wt1[i] = (f16)W1[k * 128 + n];
        } else if (i < 32768) {
            int j = i - 16384;
            int n = j >> 7, k = j & 127;
            Wt2[j] = (f16)W2[k * 128 + n];
        } else {
            int j = i - 32768;
            int n = j >> 7, k = j & 127;
            Wtf[j] = (f16)Wf[k * 64 + n];
        }
    }
}

// ELL build: one atomic per edge, direct slot write (R9 form — best measured).
__global__ void k_fill(const int* __restrict__ src, const int* __restrict__ dst, int E,
                       int* __restrict__ cnt, int* __restrict__ ell, int N) {
    int e = blockIdx.x * blockDim.x + threadIdx.x;
    if (e >= E) return;
    int d = dst[e], s = src[e];
    if ((unsigned)d >= (unsigned)N || (unsigned)s >= (unsigned)N) return;
    int p = atomicAdd(&cnt[d], 1);
    if (p < ELLW) ell[d * ELLW + p] = s;
}

// ------------------------------ MFMA GEMM ----------------------------------
// M16[m][n] = ( A[m][:] @ W[:][n] ) * rsqrt(cnt[m]+1),  K=128 fixed.
// AF32: A is fp32 (layer 1, conversion fused into fragment load).
template <int OUT, bool AF32>
__global__ __launch_bounds__(256) void k_gemm_mfma(const void* __restrict__ Av,
                                                   const f16* __restrict__ Wt,
                                                   const int* __restrict__ cnt,
                                                   f16* __restrict__ M,
                                                   int N) {
    constexpr int K  = 128;
    constexpr int CW = OUT / 64;          // col-tiles per wave (2 or 1)
    __shared__ char smem[OUT * K * 2];    // W (swizzled), then reused as out-tile
    __shared__ float dl[64];

    const int t    = threadIdx.x;
    const int w    = t >> 6;
    const int lane = t & 63;
    const int ln   = lane & 15;
    const int lh   = lane >> 4;
    const int row0 = blockIdx.x * 64;

    {
        constexpr int NCH = OUT * 16;     // 16 x 16B chunks per 256B row
        for (int j = t; j < NCH; j += 256) {
            int n = j >> 4;
            uint32_t byte = (uint32_t)j * 16;
            uint32_t swz  = byte ^ (uint32_t)((n & 7) << 4);
            *(f16x8*)(smem + swz) = *(const f16x8*)&Wt[(size_t)j * 8];
        }
        if (t < 64) {
            int r = row0 + t;
            dl[t] = rsqrtf((float)(cnt[r < N ? r : (N - 1)] + 1));
        }
    }
    __syncthreads();

    f16x8 bfr[CW][4];
    const int c0 = w * CW;
#pragma unroll
    for (int c = 0; c < CW; ++c) {
        int n = (c0 + c) * 16 + ln;
#pragma unroll
        for (int q = 0; q < 4; ++q) {
            uint32_t byte = (uint32_t)(n * 256 + q * 64 + lh * 16);
            uint32_t swz  = byte ^ (uint32_t)((n & 7) << 4);
            bfr[c][q] = *(const f16x8*)(smem + swz);
        }
    }
    __syncthreads();

    f32x4 acc[4][CW];
#pragma unroll
    for (int s = 0; s < 4; ++s)
#pragma unroll
        for (int c = 0; c < CW; ++c)
            acc[s][c] = f32x4{0.f, 0.f, 0.f, 0.f};

#pragma unroll
    for (int s = 0; s < 4; ++s) {
        int m = row0 + s * 16 + ln;
        const size_t mrow = (size_t)(m < N ? m : (N - 1)) * K;
#pragma unroll
        for (int q = 0; q < 4; ++q) {
            f16x8 a;
            if constexpr (AF32) {
                const float* ap = (const float*)Av + mrow + q * 32 + lh * 8;
                float4 x0 = *(const float4*)ap;
                float4 x1 = *(const float4*)(ap + 4);
                a = f16x8{ (f16)x0.x, (f16)x0.y, (f16)x0.z, (f16)x0.w,
                           (f16)x1.x, (f16)x1.y, (f16)x1.z, (f16)x1.w };
            } else {
                a = *(const f16x8*)((const f16*)Av + mrow + q * 32 + lh * 8);
            }
#pragma unroll
            for (int c = 0; c < CW; ++c)
                acc[s][c] = __builtin_amdgcn_mfma_f32_16x16x32_f16(a, bfr[c][q], acc[s][c], 0, 0, 0);
        }
    }

    f16* ot = (f16*)smem;
#pragma unroll
    for (int s = 0; s < 4; ++s) {
#pragma unroll
        for (int c = 0; c < CW; ++c) {
            int col = (c0 + c) * 16 + ln;
#pragma unroll
            for (int r = 0; r < 4; ++r) {
                int rl = s * 16 + lh * 4 + r;
                ot[rl * OUT + col] = (f16)(acc[s][c][r] * dl[rl]);
            }
        }
    }
    __syncthreads();

    constexpr int CPR = OUT / 8;          // 16B chunks per row
    for (int j = t; j < 64 * CPR; j += 256) {
        int rl = j / CPR;
        if (row0 + rl < N)
            *(f16x8*)&M[(size_t)(row0 + rl) * OUT + (j % CPR) * 8] =
                *(const f16x8*)&ot[(size_t)j * 8];
    }
}

// ------------------------------ aggregation --------------------------------
// HALF-WAVE per node (2 nodes/wave, 8 nodes/block). Within a half: 2 quarters
// (16 lanes x f16x8 = 256B row) x unroll 16 = 32 edges per masked round,
// 16 row-loads in flight per half-wave. deg<=32 (97%) -> ONE memory round.
// Masked lanes read slot 0 (always written when deg>=1). dinv inline from cnt.
__global__ __launch_bounds__(256) void k_agg128_f16(const f16* __restrict__ M16,
                                                    const int* __restrict__ ell,
                                                    const int* __restrict__ cnt,
                                                    const float* __restrict__ bias,
                                                    f16* __restrict__ H16, int N) {
    const int lane = threadIdx.x & (WAVE - 1);
    const int sub  = lane >> 5;            // half 0/1
    const int q    = (lane & 31) >> 4;     // quarter within half: 0/1
    const int fl   = lane & 15;            // feature lane
    const int fo   = fl * 8;               // feats fo..fo+7
    const int node = blockIdx.x * 8 + ((threadIdx.x >> 6) << 1) + sub;
    if (node >= N) return;

    float a[8] = {0.f, 0.f, 0.f, 0.f, 0.f, 0.f, 0.f, 0.f};
    if (q == 0) {   // self-loop term
        f16x8 v = *(const f16x8*)&M16[(size_t)node * 128 + fo];
#pragma unroll
        for (int i = 0; i < 8; ++i) a[i] = (float)v[i];
    }

    const int deg = cnt[node];
    const int e1  = deg < ELLW ? deg : ELLW;
    const int* erow = ell + (size_t)node * ELLW;
    for (int base = 0; base < e1; base += 32) {
        int   s[16];
        float w[16];
#pragma unroll
        for (int j = 0; j < 16; ++j) {
            int i = base + 2 * j + q;
            bool ok = i < e1;
            s[j] = erow[ok ? i : 0];
            w[j] = ok ? 1.f : 0.f;
        }
        f16x8 v[16];
#pragma unroll
        for (int j = 0; j < 16; ++j)
            v[j] = *(const f16x8*)&M16[(size_t)s[j] * 128 + fo];
#pragma unroll
        for (int j = 0; j < 16; ++j)
#pragma unroll
            for (int i = 0; i < 8; ++i)
                a[i] += w[j] * (float)v[j][i];
    }

#pragma unroll
    for (int i = 0; i < 8; ++i) a[i] += __shfl_xor(a[i], 16);

    if (q == 0) {
        const float dn = rsqrtf((float)(deg + 1));
        float4 b0 = *(const float4*)&bias[fo];
        float4 b1 = *(const float4*)&bias[fo + 4];
        f16x8 o;
        o[0] = (f16)fmaxf(a[0] * dn + b0.x, 0.f);
        o[1] = (f16)fmaxf(a[1] * dn + b0.y, 0.f);
        o[2] = (f16)fmaxf(a[2] * dn + b0.z, 0.f);
        o[3] = (f16)fmaxf(a[3] * dn + b0.w, 0.f);
        o[4] = (f16)fmaxf(a[4] * dn + b1.x, 0.f);
        o[5] = (f16)fmaxf(a[5] * dn + b1.y, 0.f);
        o[6] = (f16)fmaxf(a[6] * dn + b1.z, 0.f);
        o[7] = (f16)fmaxf(a[7] * dn + b1.w, 0.f);
        *(f16x8*)&H16[(size_t)node * 128 + fo] = o;
    }
}

// Final layer: 64 feats (128B row = 16 lanes x f16x4); half-wave per node,
// 32 edges per masked round; fused bias + log_softmax.
__global__ __launch_bounds__(256) void k_agg64_lsm(const f16* __restrict__ M16,
                                                   const int* __restrict__ ell,
                                                   const int* __restrict__ cnt,
                                                   const float* __restrict__ bias,
                                                   float* __restrict__ Y, int N) {
    const int lane = threadIdx.x & (WAVE - 1);
    const int sub  = lane >> 5;
    const int q    = (lane & 31) >> 4;
    const int fl   = lane & 15;            // classes 4*fl .. 4*fl+3
    const int fo   = fl * 4;
    const int node = blockIdx.x * 8 + ((threadIdx.x >> 6) << 1) + sub;
    if (node >= N) return;

    float a[4] = {0.f, 0.f, 0.f, 0.f};
    if (q == 0) {
        f16x4 v = *(const f16x4*)&M16[(size_t)node * 64 + fo];
#pragma unroll
        for (int i = 0; i < 4; ++i) a[i] = (float)v[i];
    }

    const int deg = cnt[node];
    const int e1  = deg < ELLW ? deg : ELLW;
    const int* erow = ell + (size_t)node * ELLW;
    for (int base = 0; base < e1; base += 32) {
        int   s[16];
        float w[16];
#pragma unroll
        for (int j = 0; j < 16; ++j) {
            int i = base + 2 * j + q;
            bool ok = i < e1;
            s[j] = erow[ok ? i : 0];
            w[j] = ok ? 1.f : 0.f;
        }
        f16x4 v[16];
#pragma unroll
        for (int j = 0; j < 16; ++j)
            v[j] = *(const f16x4*)&M16[(size_t)s[j] * 64 + fo];
#pragma unroll
        for (int j = 0; j < 16; ++j)
#pragma unroll
            for (int i = 0; i < 4; ++i)
                a[i] += w[j] * (float)v[j][i];
    }

#pragma unroll
    for (int i = 0; i < 4; ++i) a[i] += __shfl_xor(a[i], 16);

    // logits + log_softmax across 64 classes held as 16 lanes x 4
    const float dn = rsqrtf((float)(deg + 1));
    float4 b = *(const float4*)&bias[fo];
    float v0 = a[0] * dn + b.x;
    float v1 = a[1] * dn + b.y;
    float v2 = a[2] * dn + b.z;
    float v3 = a[3] * dn + b.w;
    float m = fmaxf(fmaxf(v0, v1), fmaxf(v2, v3));
#pragma unroll
    for (int o = 8; o > 0; o >>= 1) m = fmaxf(m, __shfl_xor(m, o));   // width-16
    float s = expf(v0 - m) + expf(v1 - m) + expf(v2 - m) + expf(v3 - m);
#pragma unroll
    for (int o = 8; o > 0; o >>= 1) s += __shfl_xor(s, o);
    if (q == 0) {
        float ls = logf(s);
        float4 o4 = make_float4(v0 - m - ls, v1 - m - ls, v2 - m - ls, v3 - m - ls);
        *(float4*)&Y[(size_t)node * 64 + fo] = o4;
    }
}

// ---------------------------------------------------------------------------

extern "C" void kernel_launch(void* const* d_in, const int* in_sizes, int n_in,
                              void* d_out, int out_size, void* d_ws, size_t ws_size,
                              hipStream_t stream) {
    const float* x  = (const float*)d_in[0];
    const int*   ei = (const int*)d_in[1];
    const float* W1 = (const float*)d_in[2];
    const float* b1 = (const float*)d_in[3];
    const float* W2 = (const float*)d_in[4];
    const float* b2 = (const float*)d_in[5];
    const float* Wf = (const float*)d_in[6];
    const float* bf = (const float*)d_in[7];
    float* out = (float*)d_out;

    const int N = in_sizes[0] / 128;
    const int E = in_sizes[1] / 2;
    const int* srcv = ei;
    const int* dstv = ei + E;

    char* ws = (char*)d_ws;
    auto alloc = [&](size_t bytes) -> void* {
        void* p = ws;
        ws += (bytes + 255) & ~(size_t)255;
        return p;
    };
    int*   cnt    = (int*)alloc((size_t)N * 4 + 16);
    int*   ell    = (int*)alloc((size_t)N * ELLW * 4);
    f16*   m16    = (f16*)alloc((size_t)N * 128 * 2);
    f16*   h16    = (f16*)alloc((size_t)N * 128 * 2);
    f16*   Wt1    = (f16*)alloc(128 * 128 * 2);
    f16*   Wt2    = (f16*)alloc(128 * 128 * 2);
    f16*   Wtf    = (f16*)alloc(128 * 64 * 2);

    const int TB = 256;
    const int n4 = (N + 3) / 4;

    k_prep<<<224, TB, 0, stream>>>((int4*)cnt, n4, W1, W2, Wf, Wt1, Wt2, Wtf);
    k_fill<<<(E + TB - 1) / TB, TB, 0, stream>>>(srcv, dstv, E, cnt, ell, N);

    const int gemm_grid = (N + 63) / 64;
    const int agg_grid  = (N + 7) / 8;

    k_gemm_mfma<128, true><<<gemm_grid, 256, 0, stream>>>(x, Wt1, cnt, m16, N);
    k_agg128_f16<<<agg_grid, 256, 0, stream>>>(m16, ell, cnt, b1, h16, N);

    k_gemm_mfma<128, false><<<gemm_grid, 256, 0, stream>>>(h16, Wt2, cnt, m16, N);
    k_agg128_f16<<<agg_grid, 256, 0, stream>>>(m16, ell, cnt, b2, h16, N);

    k_gemm_mfma<64, false><<<gemm_grid, 256, 0, stream>>>(h16, Wtf, cnt, m16, N);
    k_agg64_lsm<<<agg_grid, 256, 0, stream>>>(m16, ell, cnt, bf, out, N);
}

// Round 14
// 176.794 us; speedup vs baseline: 1.3815x; 1.0733x over previous
//
#include <hip/hip_runtime.h>
#include <cstdint>
#include <cstddef>

// ---------------------------------------------------------------------------
// 3-layer GCN, fp16 message pipeline, 8 dispatches:
//   k_prep (zero cnt + cvt weights) | k_fill (ELL build) |
//   {gemm, agg} x3  (agg64 fuses bias + log_softmax)
// ELL width 64 (deg ~ Poisson(12.5); cnt counts ALL edges so dinv =
// rsqrt(deg+1) stays exact even if capped).
// Aggregation (R9 structure — best measured): half-wave per node, 2 quarters
// x f16x8 row loads, 16-edge masked round, 8 row-loads in flight per lane.
// NEW vs R9: ELL indices loaded ONCE per half-wave (coalesced) and
// distributed via __shfl — vmem insts per lane per round 16 -> 9.
// Lessons: R8 coop mega 3.7x slower; R10 atomic padding null; R11 two-phase
// build null; R12 feature-chunking -80us; R13 32-edge rounds -26us (duplicate
// masked loads + VGPR growth). rocprof per-kernel durs are cold-cache
// inflated by 256MiB flush fills — trust end-to-end dur only.
// ---------------------------------------------------------------------------

#define WAVE 64
#define ELLW 64
typedef _Float16 f16;
typedef f16  f16x4 __attribute__((ext_vector_type(4)));
typedef f16  f16x8 __attribute__((ext_vector_type(8)));
typedef float f32x4 __attribute__((ext_vector_type(4)));

// ------------------------------ setup --------------------------------------

// zero cnt (int4 stores) + all three weight transposes, one dispatch.
__global__ __launch_bounds__(256) void k_prep(int4* __restrict__ cnt4, int n4,
                                              const float* __restrict__ W1,
                                              const float* __restrict__ W2,
                                              const float* __restrict__ Wf,
                                              f16* __restrict__ Wt1,
                                              f16* __restrict__ Wt2,
                                              f16* __restrict__ Wtf) {
    const int gtid = blockIdx.x * 256 + threadIdx.x;
    const int gsz  = gridDim.x * 256;
    const int4 z = make_int4(0, 0, 0, 0);
    for (int i = gtid; i < n4; i += gsz) cnt4[i] = z;
    for (int i = gtid; i < 40960; i += gsz) {
        if (i < 16384) {
            int n = i >> 7, k = i & 127;
            Wt1[i] = (f16)W1[k * 128 + n];
        } else if (i < 32768) {
            int j = i - 16384;
            int n = j >> 7, k = j & 127;
            Wt2[j] = (f16)W2[k * 128 + n];
        } else {
            int j = i - 32768;
            int n = j >> 7, k = j & 127;
            Wtf[j] = (f16)Wf[k * 64 + n];
        }
    }
}

// ELL build: one atomic per edge, direct slot write (R9 form — best measured).
__global__ void k_fill(const int* __restrict__ src, const int* __restrict__ dst, int E,
                       int* __restrict__ cnt, int* __restrict__ ell, int N) {
    int e = blockIdx.x * blockDim.x + threadIdx.x;
    if (e >= E) return;
    int d = dst[e], s = src[e];
    if ((unsigned)d >= (unsigned)N || (unsigned)s >= (unsigned)N) return;
    int p = atomicAdd(&cnt[d], 1);
    if (p < ELLW) ell[d * ELLW + p] = s;
}

// ------------------------------ MFMA GEMM ----------------------------------
// M16[m][n] = ( A[m][:] @ W[:][n] ) * rsqrt(cnt[m]+1),  K=128 fixed.
// AF32: A is fp32 (layer 1, conversion fused into fragment load).
template <int OUT, bool AF32>
__global__ __launch_bounds__(256) void k_gemm_mfma(const void* __restrict__ Av,
                                                   const f16* __restrict__ Wt,
                                                   const int* __restrict__ cnt,
                                                   f16* __restrict__ M,
                                                   int N) {
    constexpr int K  = 128;
    constexpr int CW = OUT / 64;          // col-tiles per wave (2 or 1)
    __shared__ char smem[OUT * K * 2];    // W (swizzled), then reused as out-tile
    __shared__ float dl[64];

    const int t    = threadIdx.x;
    const int w    = t >> 6;
    const int lane = t & 63;
    const int ln   = lane & 15;
    const int lh   = lane >> 4;
    const int row0 = blockIdx.x * 64;

    {
        constexpr int NCH = OUT * 16;     // 16 x 16B chunks per 256B row
        for (int j = t; j < NCH; j += 256) {
            int n = j >> 4;
            uint32_t byte = (uint32_t)j * 16;
            uint32_t swz  = byte ^ (uint32_t)((n & 7) << 4);
            *(f16x8*)(smem + swz) = *(const f16x8*)&Wt[(size_t)j * 8];
        }
        if (t < 64) {
            int r = row0 + t;
            dl[t] = rsqrtf((float)(cnt[r < N ? r : (N - 1)] + 1));
        }
    }
    __syncthreads();

    f16x8 bfr[CW][4];
    const int c0 = w * CW;
#pragma unroll
    for (int c = 0; c < CW; ++c) {
        int n = (c0 + c) * 16 + ln;
#pragma unroll
        for (int q = 0; q < 4; ++q) {
            uint32_t byte = (uint32_t)(n * 256 + q * 64 + lh * 16);
            uint32_t swz  = byte ^ (uint32_t)((n & 7) << 4);
            bfr[c][q] = *(const f16x8*)(smem + swz);
        }
    }
    __syncthreads();

    f32x4 acc[4][CW];
#pragma unroll
    for (int s = 0; s < 4; ++s)
#pragma unroll
        for (int c = 0; c < CW; ++c)
            acc[s][c] = f32x4{0.f, 0.f, 0.f, 0.f};

#pragma unroll
    for (int s = 0; s < 4; ++s) {
        int m = row0 + s * 16 + ln;
        const size_t mrow = (size_t)(m < N ? m : (N - 1)) * K;
#pragma unroll
        for (int q = 0; q < 4; ++q) {
            f16x8 a;
            if constexpr (AF32) {
                const float* ap = (const float*)Av + mrow + q * 32 + lh * 8;
                float4 x0 = *(const float4*)ap;
                float4 x1 = *(const float4*)(ap + 4);
                a = f16x8{ (f16)x0.x, (f16)x0.y, (f16)x0.z, (f16)x0.w,
                           (f16)x1.x, (f16)x1.y, (f16)x1.z, (f16)x1.w };
            } else {
                a = *(const f16x8*)((const f16*)Av + mrow + q * 32 + lh * 8);
            }
#pragma unroll
            for (int c = 0; c < CW; ++c)
                acc[s][c] = __builtin_amdgcn_mfma_f32_16x16x32_f16(a, bfr[c][q], acc[s][c], 0, 0, 0);
        }
    }

    f16* ot = (f16*)smem;
#pragma unroll
    for (int s = 0; s < 4; ++s) {
#pragma unroll
        for (int c = 0; c < CW; ++c) {
            int col = (c0 + c) * 16 + ln;
#pragma unroll
            for (int r = 0; r < 4; ++r) {
                int rl = s * 16 + lh * 4 + r;
                ot[rl * OUT + col] = (f16)(acc[s][c][r] * dl[rl]);
            }
        }
    }
    __syncthreads();

    constexpr int CPR = OUT / 8;          // 16B chunks per row
    for (int j = t; j < 64 * CPR; j += 256) {
        int rl = j / CPR;
        if (row0 + rl < N)
            *(f16x8*)&M[(size_t)(row0 + rl) * OUT + (j % CPR) * 8] =
                *(const f16x8*)&ot[(size_t)j * 8];
    }
}

// ------------------------------ aggregation --------------------------------
// HALF-WAVE per node (2 nodes/wave, 8 nodes/block). Within a half: 2 quarters
// (16 lanes x f16x8 = 256B row) x unroll 8 = 16 edges per masked round,
// 8 row-loads in flight per lane. ELL indices: ONE coalesced load per
// half-wave lane (erow[base + (hl&15)]) + __shfl distribution (vmem 16->9).
// Masked lanes read slot 0 (always written when deg>=1). dinv inline from cnt.
__global__ __launch_bounds__(256) void k_agg128_f16(const f16* __restrict__ M16,
                                                    const int* __restrict__ ell,
                                                    const int* __restrict__ cnt,
                                                    const float* __restrict__ bias,
                                                    f16* __restrict__ H16, int N) {
    const int lane = threadIdx.x & (WAVE - 1);
    const int sub  = lane >> 5;            // half 0/1
    const int hl   = lane & 31;            // lane within half
    const int q    = hl >> 4;              // quarter within half: 0/1
    const int fl   = lane & 15;            // feature lane
    const int fo   = fl * 8;               // feats fo..fo+7
    const int node = blockIdx.x * 8 + ((threadIdx.x >> 6) << 1) + sub;
    if (node >= N) return;

    float a[8] = {0.f, 0.f, 0.f, 0.f, 0.f, 0.f, 0.f, 0.f};
    if (q == 0) {   // self-loop term
        f16x8 v = *(const f16x8*)&M16[(size_t)node * 128 + fo];
#pragma unroll
        for (int i = 0; i < 8; ++i) a[i] = (float)v[i];
    }

    const int deg = cnt[node];
    const int e1  = deg < ELLW ? deg : ELLW;
    const int* erow = ell + (size_t)node * ELLW;
    const int sbase = sub * 32;            // this half's lane-0 in the wave
    for (int base = 0; base < e1; base += 16) {
        int i0  = base + (hl & 15);
        int idx = erow[i0 < e1 ? i0 : 0];  // coalesced 16-index load
        int   s[8];
        float w[8];
#pragma unroll
        for (int j = 0; j < 8; ++j) {
            int i = base + 2 * j + q;
            s[j] = __shfl(idx, sbase + 2 * j + q);
            w[j] = (i < e1) ? 1.f : 0.f;
        }
        f16x8 v[8];
#pragma unroll
        for (int j = 0; j < 8; ++j)
            v[j] = *(const f16x8*)&M16[(size_t)s[j] * 128 + fo];
#pragma unroll
        for (int j = 0; j < 8; ++j)
#pragma unroll
            for (int i = 0; i < 8; ++i)
                a[i] += w[j] * (float)v[j][i];
    }

#pragma unroll
    for (int i = 0; i < 8; ++i) a[i] += __shfl_xor(a[i], 16);

    if (q == 0) {
        const float dn = rsqrtf((float)(deg + 1));
        float4 b0 = *(const float4*)&bias[fo];
        float4 b1 = *(const float4*)&bias[fo + 4];
        f16x8 o;
        o[0] = (f16)fmaxf(a[0] * dn + b0.x, 0.f);
        o[1] = (f16)fmaxf(a[1] * dn + b0.y, 0.f);
        o[2] = (f16)fmaxf(a[2] * dn + b0.z, 0.f);
        o[3] = (f16)fmaxf(a[3] * dn + b0.w, 0.f);
        o[4] = (f16)fmaxf(a[4] * dn + b1.x, 0.f);
        o[5] = (f16)fmaxf(a[5] * dn + b1.y, 0.f);
        o[6] = (f16)fmaxf(a[6] * dn + b1.z, 0.f);
        o[7] = (f16)fmaxf(a[7] * dn + b1.w, 0.f);
        *(f16x8*)&H16[(size_t)node * 128 + fo] = o;
    }
}

// Final layer: 64 feats (128B row = 16 lanes x f16x4); half-wave per node,
// 16 edges per masked round; shfl index broadcast; fused bias + log_softmax.
__global__ __launch_bounds__(256) void k_agg64_lsm(const f16* __restrict__ M16,
                                                   const int* __restrict__ ell,
                                                   const int* __restrict__ cnt,
                                                   const float* __restrict__ bias,
                                                   float* __restrict__ Y, int N) {
    const int lane = threadIdx.x & (WAVE - 1);
    const int sub  = lane >> 5;
    const int hl   = lane & 31;
    const int q    = hl >> 4;
    const int fl   = lane & 15;            // classes 4*fl .. 4*fl+3
    const int fo   = fl * 4;
    const int node = blockIdx.x * 8 + ((threadIdx.x >> 6) << 1) + sub;
    if (node >= N) return;

    float a[4] = {0.f, 0.f, 0.f, 0.f};
    if (q == 0) {
        f16x4 v = *(const f16x4*)&M16[(size_t)node * 64 + fo];
#pragma unroll
        for (int i = 0; i < 4; ++i) a[i] = (float)v[i];
    }

    const int deg = cnt[node];
    const int e1  = deg < ELLW ? deg : ELLW;
    const int* erow = ell + (size_t)node * ELLW;
    const int sbase = sub * 32;
    for (int base = 0; base < e1; base += 16) {
        int i0  = base + (hl & 15);
        int idx = erow[i0 < e1 ? i0 : 0];
        int   s[8];
        float w[8];
#pragma unroll
        for (int j = 0; j < 8; ++j) {
            int i = base + 2 * j + q;
            s[j] = __shfl(idx, sbase + 2 * j + q);
            w[j] = (i < e1) ? 1.f : 0.f;
        }
        f16x4 v[8];
#pragma unroll
        for (int j = 0; j < 8; ++j)
            v[j] = *(const f16x4*)&M16[(size_t)s[j] * 64 + fo];
#pragma unroll
        for (int j = 0; j < 8; ++j)
#pragma unroll
            for (int i = 0; i < 4; ++i)
                a[i] += w[j] * (float)v[j][i];
    }

#pragma unroll
    for (int i = 0; i < 4; ++i) a[i] += __shfl_xor(a[i], 16);

    // logits + log_softmax across 64 classes held as 16 lanes x 4
    const float dn = rsqrtf((float)(deg + 1));
    float4 b = *(const float4*)&bias[fo];
    float v0 = a[0] * dn + b.x;
    float v1 = a[1] * dn + b.y;
    float v2 = a[2] * dn + b.z;
    float v3 = a[3] * dn + b.w;
    float m = fmaxf(fmaxf(v0, v1), fmaxf(v2, v3));
#pragma unroll
    for (int o = 8; o > 0; o >>= 1) m = fmaxf(m, __shfl_xor(m, o));   // width-16
    float s = expf(v0 - m) + expf(v1 - m) + expf(v2 - m) + expf(v3 - m);
#pragma unroll
    for (int o = 8; o > 0; o >>= 1) s += __shfl_xor(s, o);
    if (q == 0) {
        float ls = logf(s);
        float4 o4 = make_float4(v0 - m - ls, v1 - m - ls, v2 - m - ls, v3 - m - ls);
        *(float4*)&Y[(size_t)node * 64 + fo] = o4;
    }
}

// ---------------------------------------------------------------------------

extern "C" void kernel_launch(void* const* d_in, const int* in_sizes, int n_in,
                              void* d_out, int out_size, void* d_ws, size_t ws_size,
                              hipStream_t stream) {
    const float* x  = (const float*)d_in[0];
    const int*   ei = (const int*)d_in[1];
    const float* W1 = (const float*)d_in[2];
    const float* b1 = (const float*)d_in[3];
    const float* W2 = (const float*)d_in[4];
    const float* b2 = (const float*)d_in[5];
    const float* Wf = (const float*)d_in[6];
    const float* bf = (const float*)d_in[7];
    float* out = (float*)d_out;

    const int N = in_sizes[0] / 128;
    const int E = in_sizes[1] / 2;
    const int* srcv = ei;
    const int* dstv = ei + E;

    char* ws = (char*)d_ws;
    auto alloc = [&](size_t bytes) -> void* {
        void* p = ws;
        ws += (bytes + 255) & ~(size_t)255;
        return p;
    };
    int*   cnt    = (int*)alloc((size_t)N * 4 + 16);
    int*   ell    = (int*)alloc((size_t)N * ELLW * 4);
    f16*   m16    = (f16*)alloc((size_t)N * 128 * 2);
    f16*   h16    = (f16*)alloc((size_t)N * 128 * 2);
    f16*   Wt1    = (f16*)alloc(128 * 128 * 2);
    f16*   Wt2    = (f16*)alloc(128 * 128 * 2);
    f16*   Wtf    = (f16*)alloc(128 * 64 * 2);

    const int TB = 256;
    const int n4 = (N + 3) / 4;

    k_prep<<<224, TB, 0, stream>>>((int4*)cnt, n4, W1, W2, Wf, Wt1, Wt2, Wtf);
    k_fill<<<(E + TB - 1) / TB, TB, 0, stream>>>(srcv, dstv, E, cnt, ell, N);

    const int gemm_grid = (N + 63) / 64;
    const int agg_grid  = (N + 7) / 8;

    k_gemm_mfma<128, true><<<gemm_grid, 256, 0, stream>>>(x, Wt1, cnt, m16, N);
    k_agg128_f16<<<agg_grid, 256, 0, stream>>>(m16, ell, cnt, b1, h16, N);

    k_gemm_mfma<128, false><<<gemm_grid, 256, 0, stream>>>(h16, Wt2, cnt, m16, N);
    k_agg128_f16<<<agg_grid, 256, 0, stream>>>(m16, ell, cnt, b2, h16, N);

    k_gemm_mfma<64, false><<<gemm_grid, 256, 0, stream>>>(h16, Wtf, cnt, m16, N);
    k_agg64_lsm<<<agg_grid, 256, 0, stream>>>(m16, ell, cnt, bf, out, N);
}

// Round 15
// 160.812 us; speedup vs baseline: 1.5188x; 1.0994x over previous
//
#include <hip/hip_runtime.h>
#include <cstdint>
#include <cstddef>

// ---------------------------------------------------------------------------
// 3-layer GCN, fp16 message pipeline, 8 dispatches:
//   k_prep (zero cnt + cvt weights) | k_fill (ELL build) |
//   {gemm, agg} x3  (agg64 fuses bias + log_softmax)
// Graph structure: ELL table, width 64 (deg ~ Poisson(12.5), P(deg>64)<1e-30;
// cnt counts ALL edges so dinv = rsqrt(deg+1) stays exact even if capped).
// dinv is computed inline from cnt — no dinv array, no scan, no scatter.
// FINAL FORM = R9 (163.7us), the measured optimum. Perturbation ledger:
//   R8  cooperative mega-kernel      +581us (grid.sync over 8 XCDs)
//   R10 atomic cache-line padding    +6us   (atomics not line-serialized)
//   R11 two-phase bucketed build     +1us   (write scatter absorbed by L2/L3)
//   R12 feature-chunked agg          +80us  (MLP halved; L3 already absorbs)
//   R13 32-edge masked rounds        +26us  (duplicate masked loads, VGPRs)
//   R14 shfl index broadcast         +13us  (ds_bpermute serializes chain)
// rocprof per-kernel durs are cold-cache inflated by 256MiB flush fills —
// trust end-to-end dur only.
// ---------------------------------------------------------------------------

#define WAVE 64
#define ELLW 64
typedef _Float16 f16;
typedef f16  f16x4 __attribute__((ext_vector_type(4)));
typedef f16  f16x8 __attribute__((ext_vector_type(8)));
typedef float f32x4 __attribute__((ext_vector_type(4)));

// ------------------------------ setup --------------------------------------

// zero cnt (int4 stores) + all three weight transposes, one dispatch.
__global__ __launch_bounds__(256) void k_prep(int4* __restrict__ cnt4, int n4,
                                              const float* __restrict__ W1,
                                              const float* __restrict__ W2,
                                              const float* __restrict__ Wf,
                                              f16* __restrict__ Wt1,
                                              f16* __restrict__ Wt2,
                                              f16* __restrict__ Wtf) {
    const int gtid = blockIdx.x * 256 + threadIdx.x;
    const int gsz  = gridDim.x * 256;
    const int4 z = make_int4(0, 0, 0, 0);
    for (int i = gtid; i < n4; i += gsz) cnt4[i] = z;
    for (int i = gtid; i < 40960; i += gsz) {
        if (i < 16384) {
            int n = i >> 7, k = i & 127;
            Wt1[i] = (f16)W1[k * 128 + n];
        } else if (i < 32768) {
            int j = i - 16384;
            int n = j >> 7, k = j & 127;
            Wt2[j] = (f16)W2[k * 128 + n];
        } else {
            int j = i - 32768;
            int n = j >> 7, k = j & 127;
            Wtf[j] = (f16)Wf[k * 64 + n];
        }
    }
}

// ELL build: one atomic per edge, direct slot write.
__global__ void k_fill(const int* __restrict__ src, const int* __restrict__ dst, int E,
                       int* __restrict__ cnt, int* __restrict__ ell, int N) {
    int e = blockIdx.x * blockDim.x + threadIdx.x;
    if (e >= E) return;
    int d = dst[e], s = src[e];
    if ((unsigned)d >= (unsigned)N || (unsigned)s >= (unsigned)N) return;
    int p = atomicAdd(&cnt[d], 1);
    if (p < ELLW) ell[d * ELLW + p] = s;
}

// ------------------------------ MFMA GEMM ----------------------------------
// M16[m][n] = ( A[m][:] @ W[:][n] ) * rsqrt(cnt[m]+1),  K=128 fixed.
// AF32: A is fp32 (layer 1, conversion fused into fragment load).
template <int OUT, bool AF32>
__global__ __launch_bounds__(256) void k_gemm_mfma(const void* __restrict__ Av,
                                                   const f16* __restrict__ Wt,
                                                   const int* __restrict__ cnt,
                                                   f16* __restrict__ M,
                                                   int N) {
    constexpr int K  = 128;
    constexpr int CW = OUT / 64;          // col-tiles per wave (2 or 1)
    __shared__ char smem[OUT * K * 2];    // W (swizzled), then reused as out-tile
    __shared__ float dl[64];

    const int t    = threadIdx.x;
    const int w    = t >> 6;
    const int lane = t & 63;
    const int ln   = lane & 15;
    const int lh   = lane >> 4;
    const int row0 = blockIdx.x * 64;

    {
        constexpr int NCH = OUT * 16;     // 16 x 16B chunks per 256B row
        for (int j = t; j < NCH; j += 256) {
            int n = j >> 4;
            uint32_t byte = (uint32_t)j * 16;
            uint32_t swz  = byte ^ (uint32_t)((n & 7) << 4);
            *(f16x8*)(smem + swz) = *(const f16x8*)&Wt[(size_t)j * 8];
        }
        if (t < 64) {
            int r = row0 + t;
            dl[t] = rsqrtf((float)(cnt[r < N ? r : (N - 1)] + 1));
        }
    }
    __syncthreads();

    f16x8 bfr[CW][4];
    const int c0 = w * CW;
#pragma unroll
    for (int c = 0; c < CW; ++c) {
        int n = (c0 + c) * 16 + ln;
#pragma unroll
        for (int q = 0; q < 4; ++q) {
            uint32_t byte = (uint32_t)(n * 256 + q * 64 + lh * 16);
            uint32_t swz  = byte ^ (uint32_t)((n & 7) << 4);
            bfr[c][q] = *(const f16x8*)(smem + swz);
        }
    }
    __syncthreads();

    f32x4 acc[4][CW];
#pragma unroll
    for (int s = 0; s < 4; ++s)
#pragma unroll
        for (int c = 0; c < CW; ++c)
            acc[s][c] = f32x4{0.f, 0.f, 0.f, 0.f};

#pragma unroll
    for (int s = 0; s < 4; ++s) {
        int m = row0 + s * 16 + ln;
        const size_t mrow = (size_t)(m < N ? m : (N - 1)) * K;
#pragma unroll
        for (int q = 0; q < 4; ++q) {
            f16x8 a;
            if constexpr (AF32) {
                const float* ap = (const float*)Av + mrow + q * 32 + lh * 8;
                float4 x0 = *(const float4*)ap;
                float4 x1 = *(const float4*)(ap + 4);
                a = f16x8{ (f16)x0.x, (f16)x0.y, (f16)x0.z, (f16)x0.w,
                           (f16)x1.x, (f16)x1.y, (f16)x1.z, (f16)x1.w };
            } else {
                a = *(const f16x8*)((const f16*)Av + mrow + q * 32 + lh * 8);
            }
#pragma unroll
            for (int c = 0; c < CW; ++c)
                acc[s][c] = __builtin_amdgcn_mfma_f32_16x16x32_f16(a, bfr[c][q], acc[s][c], 0, 0, 0);
        }
    }

    f16* ot = (f16*)smem;
#pragma unroll
    for (int s = 0; s < 4; ++s) {
#pragma unroll
        for (int c = 0; c < CW; ++c) {
            int col = (c0 + c) * 16 + ln;
#pragma unroll
            for (int r = 0; r < 4; ++r) {
                int rl = s * 16 + lh * 4 + r;
                ot[rl * OUT + col] = (f16)(acc[s][c][r] * dl[rl]);
            }
        }
    }
    __syncthreads();

    constexpr int CPR = OUT / 8;          // 16B chunks per row
    for (int j = t; j < 64 * CPR; j += 256) {
        int rl = j / CPR;
        if (row0 + rl < N)
            *(f16x8*)&M[(size_t)(row0 + rl) * OUT + (j % CPR) * 8] =
                *(const f16x8*)&ot[(size_t)j * 8];
    }
}

// ------------------------------ aggregation --------------------------------
// HALF-WAVE per node (2 nodes/wave, 8 nodes/block). Within a half: 2 quarters
// (16 lanes x f16x8 = 256B row) x unroll 8 = 16 edges per masked round,
// 8 row-loads in flight per wave. Edge list: ELL row ell[node*64 + j].
// Masked lanes read slot 0 (always written when deg>=1). dinv inline from cnt.
__global__ __launch_bounds__(256) void k_agg128_f16(const f16* __restrict__ M16,
                                                    const int* __restrict__ ell,
                                                    const int* __restrict__ cnt,
                                                    const float* __restrict__ bias,
                                                    f16* __restrict__ H16, int N) {
    const int lane = threadIdx.x & (WAVE - 1);
    const int sub  = lane >> 5;            // half 0/1
    const int q    = (lane & 31) >> 4;     // quarter within half: 0/1
    const int fl   = lane & 15;            // feature lane
    const int fo   = fl * 8;               // feats fo..fo+7
    const int node = blockIdx.x * 8 + ((threadIdx.x >> 6) << 1) + sub;
    if (node >= N) return;

    float a[8] = {0.f, 0.f, 0.f, 0.f, 0.f, 0.f, 0.f, 0.f};
    if (q == 0) {   // self-loop term
        f16x8 v = *(const f16x8*)&M16[(size_t)node * 128 + fo];
#pragma unroll
        for (int i = 0; i < 8; ++i) a[i] = (float)v[i];
    }

    const int deg = cnt[node];
    const int e1  = deg < ELLW ? deg : ELLW;
    const int* erow = ell + (size_t)node * ELLW;
    for (int base = 0; base < e1; base += 16) {
        int   s[8];
        float w[8];
#pragma unroll
        for (int j = 0; j < 8; ++j) {
            int i = base + 2 * j + q;
            bool ok = i < e1;
            s[j] = erow[ok ? i : 0];
            w[j] = ok ? 1.f : 0.f;
        }
        f16x8 v[8];
#pragma unroll
        for (int j = 0; j < 8; ++j)
            v[j] = *(const f16x8*)&M16[(size_t)s[j] * 128 + fo];
#pragma unroll
        for (int j = 0; j < 8; ++j)
#pragma unroll
            for (int i = 0; i < 8; ++i)
                a[i] += w[j] * (float)v[j][i];
    }

#pragma unroll
    for (int i = 0; i < 8; ++i) a[i] += __shfl_xor(a[i], 16);

    if (q == 0) {
        const float dn = rsqrtf((float)(deg + 1));
        float4 b0 = *(const float4*)&bias[fo];
        float4 b1 = *(const float4*)&bias[fo + 4];
        f16x8 o;
        o[0] = (f16)fmaxf(a[0] * dn + b0.x, 0.f);
        o[1] = (f16)fmaxf(a[1] * dn + b0.y, 0.f);
        o[2] = (f16)fmaxf(a[2] * dn + b0.z, 0.f);
        o[3] = (f16)fmaxf(a[3] * dn + b0.w, 0.f);
        o[4] = (f16)fmaxf(a[4] * dn + b1.x, 0.f);
        o[5] = (f16)fmaxf(a[5] * dn + b1.y, 0.f);
        o[6] = (f16)fmaxf(a[6] * dn + b1.z, 0.f);
        o[7] = (f16)fmaxf(a[7] * dn + b1.w, 0.f);
        *(f16x8*)&H16[(size_t)node * 128 + fo] = o;
    }
}

// Final layer: 64 feats (128B row = 16 lanes x f16x4); half-wave per node,
// 16 edges per masked round; fused bias + log_softmax.
__global__ __launch_bounds__(256) void k_agg64_lsm(const f16* __restrict__ M16,
                                                   const int* __restrict__ ell,
                                                   const int* __restrict__ cnt,
                                                   const float* __restrict__ bias,
                                                   float* __restrict__ Y, int N) {
    const int lane = threadIdx.x & (WAVE - 1);
    const int sub  = lane >> 5;
    const int q    = (lane & 31) >> 4;
    const int fl   = lane & 15;            // classes 4*fl .. 4*fl+3
    const int fo   = fl * 4;
    const int node = blockIdx.x * 8 + ((threadIdx.x >> 6) << 1) + sub;
    if (node >= N) return;

    float a[4] = {0.f, 0.f, 0.f, 0.f};
    if (q == 0) {
        f16x4 v = *(const f16x4*)&M16[(size_t)node * 64 + fo];
#pragma unroll
        for (int i = 0; i < 4; ++i) a[i] = (float)v[i];
    }

    const int deg = cnt[node];
    const int e1  = deg < ELLW ? deg : ELLW;
    const int* erow = ell + (size_t)node * ELLW;
    for (int base = 0; base < e1; base += 16) {
        int   s[8];
        float w[8];
#pragma unroll
        for (int j = 0; j < 8; ++j) {
            int i = base + 2 * j + q;
            bool ok = i < e1;
            s[j] = erow[ok ? i : 0];
            w[j] = ok ? 1.f : 0.f;
        }
        f16x4 v[8];
#pragma unroll
        for (int j = 0; j < 8; ++j)
            v[j] = *(const f16x4*)&M16[(size_t)s[j] * 64 + fo];
#pragma unroll
        for (int j = 0; j < 8; ++j)
#pragma unroll
            for (int i = 0; i < 4; ++i)
                a[i] += w[j] * (float)v[j][i];
    }

#pragma unroll
    for (int i = 0; i < 4; ++i) a[i] += __shfl_xor(a[i], 16);

    // logits + log_softmax across 64 classes held as 16 lanes x 4
    const float dn = rsqrtf((float)(deg + 1));
    float4 b = *(const float4*)&bias[fo];
    float v0 = a[0] * dn + b.x;
    float v1 = a[1] * dn + b.y;
    float v2 = a[2] * dn + b.z;
    float v3 = a[3] * dn + b.w;
    float m = fmaxf(fmaxf(v0, v1), fmaxf(v2, v3));
#pragma unroll
    for (int o = 8; o > 0; o >>= 1) m = fmaxf(m, __shfl_xor(m, o));   // width-16
    float s = expf(v0 - m) + expf(v1 - m) + expf(v2 - m) + expf(v3 - m);
#pragma unroll
    for (int o = 8; o > 0; o >>= 1) s += __shfl_xor(s, o);
    if (q == 0) {
        float ls = logf(s);
        float4 o4 = make_float4(v0 - m - ls, v1 - m - ls, v2 - m - ls, v3 - m - ls);
        *(float4*)&Y[(size_t)node * 64 + fo] = o4;
    }
}

// ---------------------------------------------------------------------------

extern "C" void kernel_launch(void* const* d_in, const int* in_sizes, int n_in,
                              void* d_out, int out_size, void* d_ws, size_t ws_size,
                              hipStream_t stream) {
    const float* x  = (const float*)d_in[0];
    const int*   ei = (const int*)d_in[1];
    const float* W1 = (const float*)d_in[2];
    const float* b1 = (const float*)d_in[3];
    const float* W2 = (const float*)d_in[4];
    const float* b2 = (const float*)d_in[5];
    const float* Wf = (const float*)d_in[6];
    const float* bf = (const float*)d_in[7];
    float* out = (float*)d_out;

    const int N = in_sizes[0] / 128;
    const int E = in_sizes[1] / 2;
    const int* srcv = ei;
    const int* dstv = ei + E;

    char* ws = (char*)d_ws;
    auto alloc = [&](size_t bytes) -> void* {
        void* p = ws;
        ws += (bytes + 255) & ~(size_t)255;
        return p;
    };
    int*   cnt    = (int*)alloc((size_t)N * 4 + 16);
    int*   ell    = (int*)alloc((size_t)N * ELLW * 4);
    f16*   m16    = (f16*)alloc((size_t)N * 128 * 2);
    f16*   h16    = (f16*)alloc((size_t)N * 128 * 2);
    f16*   Wt1    = (f16*)alloc(128 * 128 * 2);
    f16*   Wt2    = (f16*)alloc(128 * 128 * 2);
    f16*   Wtf    = (f16*)alloc(128 * 64 * 2);

    const int TB = 256;
    const int n4 = (N + 3) / 4;

    k_prep<<<224, TB, 0, stream>>>((int4*)cnt, n4, W1, W2, Wf, Wt1, Wt2, Wtf);
    k_fill<<<(E + TB - 1) / TB, TB, 0, stream>>>(srcv, dstv, E, cnt, ell, N);

    const int gemm_grid = (N + 63) / 64;
    const int agg_grid  = (N + 7) / 8;

    k_gemm_mfma<128, true><<<gemm_grid, 256, 0, stream>>>(x, Wt1, cnt, m16, N);
    k_agg128_f16<<<agg_grid, 256, 0, stream>>>(m16, ell, cnt, b1, h16, N);

    k_gemm_mfma<128, false><<<gemm_grid, 256, 0, stream>>>(h16, Wt2, cnt, m16, N);
    k_agg128_f16<<<agg_grid, 256, 0, stream>>>(m16, ell, cnt, b2, h16, N);

    k_gemm_mfma<64, false><<<gemm_grid, 256, 0, stream>>>(h16, Wtf, cnt, m16, N);
    k_agg64_lsm<<<agg_grid, 256, 0, stream>>>(m16, ell, cnt, bf, out, N);
}